// Round 1
// 187.965 us; speedup vs baseline: 1.0048x; 1.0048x over previous
//
#include <hip/hip_runtime.h>

// Problem constants (match reference)
constexpr int Bn = 4, Cn = 512, Ln = 2048, CIn = 512, Hn = 8, Dn = 64;
constexpr int COn = 3 * CIn;  // 1536 stacked output channels: [theta; phi; g]

typedef unsigned short u16;
typedef unsigned int u32;
typedef __attribute__((ext_vector_type(8))) short bfrag;  // 8 x bf16 (4 VGPRs)
typedef __attribute__((ext_vector_type(4))) float facc;   // 4 x f32 acc

// 1/sqrt(D) * log2(e): folded into theta weights/bias so QK^T lands in log2 domain
#define SCF 0.180336879f

__device__ __forceinline__ facc mfma16(bfrag a, bfrag b, facc c) {
  return __builtin_amdgcn_mfma_f32_16x16x32_bf16(a, b, c, 0, 0, 0);
}

__device__ __forceinline__ void async16(const void* g, void* l) {
  __builtin_amdgcn_global_load_lds((const __attribute__((address_space(1))) void*)g,
                                   (__attribute__((address_space(3))) void*)l, 16, 0, 0);
}

__device__ __forceinline__ u16 f2bf(float x) {  // RNE float->bf16
  union { float f; u32 u; } v; v.f = x;
  u32 r = v.u + 0x7FFFu + ((v.u >> 16) & 1u);
  return (u16)(r >> 16);
}

__device__ __forceinline__ u16 f2bf_fast(float x) {  // round-half-up, 2 ops
  union { float f; u32 u; } v; v.f = x;
  return (u16)((v.u + 0x8000u) >> 16);
}

// pack 2 floats -> bf16x2 in one u32: 2 round-adds + 1 v_perm
__device__ __forceinline__ u32 pkbf(float lof, float hif) {
  union { float f; u32 u; } a, b; a.f = lof; b.f = hif;
  return __builtin_amdgcn_perm(b.u + 0x8000u, a.u + 0x8000u, 0x07060302u);
}

__device__ __forceinline__ float bflo(u32 u) { return __uint_as_float(u << 16); }
__device__ __forceinline__ float bfhi(u32 u) { return __uint_as_float(u & 0xFFFF0000u); }

// Swizzled frag read for row-stride-64-u16 (128B) tiles: granule gi (16B units)
// of row `row` lives at position gi ^ (row&7). Conflict-free b128 reads.
__device__ __forceinline__ bfrag fr8(const u16* base, int row, int gi) {
  return *(const bfrag*)&base[row * 64 + ((gi ^ (row & 7)) * 8)];
}

// ------- kernel 1: fused weights->bf16 + BN-stat zero + x transpose -------
// grid (64,16,5): z<4 -> xpose batch z; z==4 -> weight convert (1024 blocks).
__global__ void k_misc(const float* __restrict__ x, const float* __restrict__ gw,
                       const float* __restrict__ tw, const float* __restrict__ pw,
                       const float* __restrict__ ww, u16* __restrict__ xT,
                       u16* __restrict__ Wcat, u16* __restrict__ Ww,
                       float* __restrict__ stats) {
  int b = blockIdx.z;
  if (b == 4) {  // weight convert path
    int i = (blockIdx.y * 64 + blockIdx.x) * 256 + threadIdx.x;
    if (i < CIn * Cn) {
      Wcat[i]                = f2bf(tw[i] * SCF);  // theta (Q), pre-scaled
      Wcat[CIn * Cn + i]     = f2bf(pw[i]);        // phi   (K)
      Wcat[2 * CIn * Cn + i] = f2bf(gw[i]);        // g     (V)
      Ww[i]                  = f2bf(ww[i]);
    }
    if (i < 2 * Cn) stats[i] = 0.f;  // d_ws is poisoned each launch
    return;
  }
  __shared__ float tile[32][33];
  int l0 = blockIdx.x * 32, c0 = blockIdx.y * 32;
  int tx = threadIdx.x & 31, ty = threadIdx.x >> 5;
  const float* xb = x + (size_t)b * Cn * Ln;
  for (int k = 0; k < 4; k++)
    tile[ty + k * 8][tx] = xb[(size_t)(c0 + ty + k * 8) * Ln + l0 + tx];
  __syncthreads();
  u16* xtb = xT + (size_t)b * Ln * Cn;
  int cc = (threadIdx.x & 15) * 2, r0 = threadIdx.x >> 4;
  for (int k = 0; k < 2; k++) {
    int ll = r0 + k * 16;
    u32 pk = pkbf(tile[cc][ll], tile[cc + 1][ll]);
    *(u32*)&xtb[(size_t)(l0 + ll) * Cn + c0 + cc] = pk;
  }
}

// ------------- GEMM core: C[128,128] = A[128,K] * Bt[128,K]^T -------------
__device__ __forceinline__ void stage128x32(const u16* g, int K, int k0, u16* lds,
                                            int w, int l) {
  int gsw = ((l & 3) ^ ((l >> 3) & 3)) * 8;
  for (int jj = 0; jj < 2; jj++) {
    int j = w * 2 + jj;
    const u16* ga = g + (size_t)(j * 16 + (l >> 2)) * K + k0 + gsw;
    async16(ga, (char*)lds + j * 1024 + l * 16);
  }
}

// SWAP=1 computes C^T tiles (A-operand = Bt rows) for packed transposed stores.
template <int SWAP>
__device__ __forceinline__ void gemm_core(const u16* A, const u16* Bt, int K,
                                          u16* As, u16* Bs, facc acc[4][4],
                                          int w, int l) {
  int quad = l >> 4, lo = l & 15;
  int mw = (w >> 1) * 64, nw = (w & 1) * 64;
  int rsw = (lo >> 1) & 3;
  for (int k0 = 0; k0 < K; k0 += 32) {
    stage128x32(A, K, k0, As, w, l);
    stage128x32(Bt, K, k0, Bs, w, l);
    __syncthreads();
    bfrag af[4], bfv[4];
    for (int mi = 0; mi < 4; mi++)
      af[mi] = *(const bfrag*)&As[(mw + mi * 16 + lo) * 32 + ((quad ^ rsw) * 8)];
    for (int ni = 0; ni < 4; ni++)
      bfv[ni] = *(const bfrag*)&Bs[(nw + ni * 16 + lo) * 32 + ((quad ^ rsw) * 8)];
    for (int mi = 0; mi < 4; mi++)
      for (int ni = 0; ni < 4; ni++)
        acc[mi][ni] = SWAP ? mfma16(bfv[ni], af[mi], acc[mi][ni])
                           : mfma16(af[mi], bfv[ni], acc[mi][ni]);
    __syncthreads();
  }
}

// 64xK * Bt[128,K]^T variant (for k_wgemm)
__device__ __forceinline__ void gemm_core64(const u16* A, const u16* Bt, int K,
                                            u16* As, u16* Bs, facc acc[2][4],
                                            int w, int l) {
  int quad = l >> 4, lo = l & 15;
  int mw = (w >> 1) * 32, nw = (w & 1) * 64;
  int rsw = (lo >> 1) & 3;
  int gsw = ((l & 3) ^ ((l >> 3) & 3)) * 8;
  for (int k0 = 0; k0 < K; k0 += 32) {
    async16(A + (size_t)(w * 16 + (l >> 2)) * K + k0 + gsw, (char*)As + w * 1024 + l * 16);
    stage128x32(Bt, K, k0, Bs, w, l);
    __syncthreads();
    bfrag af[2], bfv[4];
    for (int mi = 0; mi < 2; mi++)
      af[mi] = *(const bfrag*)&As[(mw + mi * 16 + lo) * 32 + ((quad ^ rsw) * 8)];
    for (int ni = 0; ni < 4; ni++)
      bfv[ni] = *(const bfrag*)&Bs[(nw + ni * 16 + lo) * 32 + ((quad ^ rsw) * 8)];
    for (int mi = 0; mi < 2; mi++)
      for (int ni = 0; ni < 4; ni++)
        acc[mi][ni] = mfma16(af[mi], bfv[ni], acc[mi][ni]);
    __syncthreads();
  }
}

// ---------------- kernel 2: fused projection GEMM + head-split epilogue ----------------
__global__ __launch_bounds__(256) void k_proj(
    const u16* __restrict__ Wcat, const u16* __restrict__ xT,
    const float* __restrict__ tb, const float* __restrict__ pb,
    const float* __restrict__ gb, u16* __restrict__ Q, u16* __restrict__ Kb,
    u16* __restrict__ Vt) {
  __shared__ __align__(16) u16 As[128 * 32];
  __shared__ __align__(16) u16 Bs[128 * 32];
  int w = threadIdx.x >> 6, l = threadIdx.x & 63;
  int quad = l >> 4, lo = l & 15;
  int m0 = blockIdx.y * 128, n0 = blockIdx.x * 128, b = blockIdx.z;
  int chunk = m0 >> 9;  // 128-tiles never straddle 512-row chunks
  facc acc[4][4] = {};
  const u16* Ap = Wcat + (size_t)m0 * Cn;
  const u16* Bp = xT + ((size_t)b * Ln + n0) * Cn;
  int mw = (w >> 1) * 64, nw = (w & 1) * 64;
  if (chunk < 2) {
    gemm_core<0>(Ap, Bp, Cn, As, Bs, acc, w, l);
    const float* bias = (chunk == 0) ? tb : pb;
    float bs = (chunk == 0) ? SCF : 1.0f;
    for (int mi = 0; mi < 4; mi++) {
      int mo = (m0 + mw + mi * 16) & 511;
      int hh = mo >> 6;
      int db = (mo & 63) + quad * 4;
      int bi = mo + quad * 4;
      u16* dst0 = ((chunk == 0) ? Q : Kb) + (size_t)(b * Hn + hh) * Ln * 64 + db;
      float b0 = bias[bi] * bs, b1 = bias[bi + 1] * bs;
      float b2 = bias[bi + 2] * bs, b3 = bias[bi + 3] * bs;
      for (int ni = 0; ni < 4; ni++) {
        int lcol = n0 + nw + ni * 16 + lo;
        facc a = acc[mi][ni];
        uint2 pk;
        pk.x = pkbf(a[0] + b0, a[1] + b1);
        pk.y = pkbf(a[2] + b2, a[3] + b3);
        *(uint2*)(dst0 + (size_t)lcol * 64) = pk;
      }
    }
  } else {  // g -> Vt [B,H,D,L], transposed accumulation, packed-l stores
    gemm_core<1>(Ap, Bp, Cn, As, Bs, acc, w, l);
    for (int mi = 0; mi < 4; mi++) {
      int ch = (m0 + mw + mi * 16 + lo) & 511;  // channel per lane
      int hh = ch >> 6, d = ch & 63;
      float bias = gb[ch];
      u16* dst0 = Vt + ((size_t)(b * Hn + hh) * Dn + d) * Ln;
      for (int ni = 0; ni < 4; ni++) {
        int l0 = n0 + nw + ni * 16 + quad * 4;  // 4 consecutive l in acc regs
        facc a = acc[mi][ni];
        uint2 pk;
        pk.x = pkbf(a[0] + bias, a[1] + bias);
        pk.y = pkbf(a[2] + bias, a[3] + bias);
        *(uint2*)(dst0 + l0) = pk;
      }
    }
  }
}

// ---------------- kernel 3: flash attention, fixed-max softmax, NO split ----------------
// R8: same 128-q tile / 48KB LDS / K-tile-64-dbuf body as the 57.5us R3
// version, but 8 waves x 16 q-rows instead of 4 x 32. Counters showed
// MfmaUtil 23% + VALUBusy 37% + Occ 17% (2 waves/SIMD): latency-bound on the
// QK->exp->pack->LDS->PV chain. 512 threads -> 4 waves/SIMD fills the stalls
// with no change in traffic, LDS layout, or per-block work.
__global__ __launch_bounds__(512, 4) void k_attn(
    const u16* __restrict__ Q, const u16* __restrict__ Kb,
    const u16* __restrict__ Vt, u16* __restrict__ yT) {
  __shared__ __align__(16) u16 lds[24576];  // Ks[2][4096] | Vs[2][4096] | QPs[8192]
  u16* Ks = lds;
  u16* Vs = lds + 8192;
  u16* QPs = lds + 16384;
  int w = threadIdx.x >> 6, l = threadIdx.x & 63;  // w in 0..7
  int quad = l >> 4, lo = l & 15;
  int q0 = blockIdx.x * 128, h = blockIdx.y, b = blockIdx.z;
  size_t bh = (size_t)b * Hn + h;
  const u16* Qg = Q + bh * Ln * 64;
  const u16* Kg = Kb + bh * Ln * 64;
  const u16* Vg = Vt + bh * (size_t)Dn * Ln;

  int rin = l >> 3;
  int gg = ((l & 7) ^ rin) * 8;

  for (int jj = 0; jj < 2; jj++) {  // wave stages its OWN 16 Q rows
    int j = w * 2 + jj;
    async16(Qg + (size_t)(q0 + j * 8 + rin) * 64 + gg, (char*)QPs + j * 1024 + l * 16);
  }
  // K/V tile 0 -> buf 0: 8 waves x 1 row-group each
  async16(Kg + (size_t)(w * 8 + rin) * 64 + gg, (char*)Ks + w * 1024 + l * 16);
  async16(Vg + (size_t)(w * 8 + rin) * Ln + gg, (char*)Vs + w * 1024 + l * 16);
  __syncthreads();
  bfrag qf[2];  // wave-private rows, hoisted before P overwrites QPs
  for (int c = 0; c < 2; c++)
    qf[c] = fr8(QPs, w * 16 + lo, c * 4 + quad);

  facc o[4] = {};  // O^T[d = mi*16+quad*4+r][q = lo]
  float l_i = 0.f;

  for (int t = 0; t < 32; t++) {  // full 2048 kpos
    const u16* Kc = Ks + (t & 1) * 4096;
    const u16* Vc = Vs + (t & 1) * 4096;
    if (t < 31) {  // prefetch next tile into other buffer
      int nb = (~t & 1) * 4096;
      int kbase = (t + 1) * 64;
      async16(Kg + (size_t)(kbase + w * 8 + rin) * 64 + gg,
              (char*)(Ks + nb) + w * 1024 + l * 16);
      async16(Vg + (size_t)(w * 8 + rin) * Ln + kbase + gg,
              (char*)(Vs + nb) + w * 1024 + l * 16);
    }
    int row = w * 16 + lo;
    for (int ni = 0; ni < 4; ni++) {
      bfrag kf0 = fr8(Kc, ni * 16 + lo, quad);
      bfrag kf1 = fr8(Kc, ni * 16 + lo, 4 + quad);
      facc z = {};
      facc stv = mfma16(kf1, qf[1], mfma16(kf0, qf[0], z));
      float p0 = __builtin_amdgcn_exp2f(stv[0]);
      float p1 = __builtin_amdgcn_exp2f(stv[1]);
      float p2 = __builtin_amdgcn_exp2f(stv[2]);
      float p3 = __builtin_amdgcn_exp2f(stv[3]);
      l_i += (p0 + p1) + (p2 + p3);
      uint2 pk;
      pk.x = pkbf(p0, p1);
      pk.y = pkbf(p2, p3);
      int gi = ni * 2 + (quad >> 1);
      *(uint2*)&QPs[row * 64 + ((gi ^ (row & 7)) * 8) + (quad & 1) * 4] = pk;
    }
    bfrag pb2[2];
    for (int c = 0; c < 2; c++)
      pb2[c] = fr8(QPs, row, c * 4 + quad);
    for (int mi = 0; mi < 4; mi++) {
      bfrag vf0 = fr8(Vc, mi * 16 + lo, quad);
      bfrag vf1 = fr8(Vc, mi * 16 + lo, 4 + quad);
      o[mi] = mfma16(vf1, pb2[1], mfma16(vf0, pb2[0], o[mi]));
    }
    __syncthreads();
  }
  // epilogue: normalize and write yT [B,L,CI] directly (no partials)
  float lt = l_i;
  lt += __shfl_xor(lt, 16);
  lt += __shfl_xor(lt, 32);
  float inv = 1.0f / lt;
  int q = q0 + w * 16 + lo;
  u16* dst = yT + ((size_t)b * Ln + q) * CIn + h * 64;
  for (int mi = 0; mi < 4; mi++) {
    uint2 pk;
    pk.x = pkbf(o[mi][0] * inv, o[mi][1] * inv);
    pk.y = pkbf(o[mi][2] * inv, o[mi][3] * inv);
    *(uint2*)(dst + mi * 16 + quad * 4) = pk;
  }
}

// ---------------- kernel 4: W GEMM (64x128 tiles) + BN statistics ----------------
__global__ __launch_bounds__(256) void k_wgemm(
    const u16* __restrict__ Ww, const u16* __restrict__ yT,
    const float* __restrict__ wb, u16* __restrict__ wy,
    float* __restrict__ stats) {
  __shared__ __align__(16) u16 As[64 * 32];
  __shared__ __align__(16) u16 Bs[128 * 32];
  int w = threadIdx.x >> 6, l = threadIdx.x & 63;
  int quad = l >> 4, lo = l & 15;
  int m0 = blockIdx.y * 64, n0 = blockIdx.x * 128, b = blockIdx.z;
  facc acc[2][4] = {};
  gemm_core64(Ww + (size_t)m0 * CIn, yT + ((size_t)b * Ln + n0) * CIn, CIn, As, Bs, acc, w, l);
  int mw = (w >> 1) * 32, nw = (w & 1) * 64;
  for (int mi = 0; mi < 2; mi++) {
    int cb = m0 + mw + mi * 16 + quad * 4;
    for (int r = 0; r < 4; r++) {
      float bias = wb[cb + r];
      float s = 0.f, q = 0.f;
      for (int ni = 0; ni < 4; ni++) {
        float v = acc[mi][ni][r] + bias;
        wy[((size_t)b * Cn + cb + r) * Ln + n0 + nw + ni * 16 + lo] = f2bf_fast(v);
        s += v; q += v * v;  // stats from fp32 pre-round values
      }
      for (int mask = 1; mask < 16; mask <<= 1) {
        s += __shfl_xor(s, mask);
        q += __shfl_xor(q, mask);
      }
      if (lo == 0) {
        atomicAdd(&stats[cb + r], s);
        atomicAdd(&stats[Cn + cb + r], q);
      }
    }
  }
}

// ---------------- kernel 5: BN apply (bf16 in, f32 out) ----------------
__global__ void k_bn(const u16* __restrict__ wy, const float* __restrict__ stats,
                     const float* __restrict__ gam, const float* __restrict__ bet,
                     float* __restrict__ out) {
  int i = blockIdx.x * 256 + threadIdx.x;
  size_t idx = (size_t)i * 8;
  int c = (int)((idx >> 11) & (Cn - 1));  // [B,C,L], L=2^11
  const float invN = 1.f / (Bn * Ln);
  float mean = stats[c] * invN;
  float var = stats[Cn + c] * invN - mean * mean;
  float scl = gam[c] * rsqrtf(var + 1e-5f);
  float sh = bet[c] - mean * scl;
  uint4 v = *(const uint4*)(wy + idx);
  float4 o0, o1;
  o0.x = bflo(v.x) * scl + sh; o0.y = bfhi(v.x) * scl + sh;
  o0.z = bflo(v.y) * scl + sh; o0.w = bfhi(v.y) * scl + sh;
  o1.x = bflo(v.z) * scl + sh; o1.y = bfhi(v.z) * scl + sh;
  o1.z = bflo(v.w) * scl + sh; o1.w = bfhi(v.w) * scl + sh;
  *(float4*)(out + idx) = o0;
  *(float4*)(out + idx + 4) = o1;
}

extern "C" void kernel_launch(void* const* d_in, const int* in_sizes, int n_in,
                              void* d_out, int out_size, void* d_ws, size_t ws_size,
                              hipStream_t stream) {
  const float* x   = (const float*)d_in[0];
  const float* g_w = (const float*)d_in[1];
  const float* g_b = (const float*)d_in[2];
  const float* t_w = (const float*)d_in[3];
  const float* t_b = (const float*)d_in[4];
  const float* p_w = (const float*)d_in[5];
  const float* p_b = (const float*)d_in[6];
  const float* w_w = (const float*)d_in[7];
  const float* w_b = (const float*)d_in[8];
  const float* gam = (const float*)d_in[9];
  const float* bet = (const float*)d_in[10];
  float* out = (float*)d_out;

  char* ws = (char*)d_ws;
  size_t off = 0;
  auto alloc = [&](size_t bytes) {
    char* p = ws + off; off += (bytes + 255) & ~(size_t)255; return p;
  };
  u16*  xT   = (u16*)alloc((size_t)Bn * Ln * Cn * 2);      // x^T bf16        8.4MB
  u16*  Wcat = (u16*)alloc((size_t)COn * Cn * 2);          // [theta;phi;g]   1.6MB
  u16*  Ww   = (u16*)alloc((size_t)Cn * CIn * 2);          // w_w bf16        0.5MB
  u16*  Qb   = (u16*)alloc((size_t)Bn * Hn * Ln * Dn * 2); // theta [B,H,L,D] 8.4MB
  u16*  Kb   = (u16*)alloc((size_t)Bn * Hn * Ln * Dn * 2); // phi   [B,H,L,D] 8.4MB
  u16*  Vt   = (u16*)alloc((size_t)Bn * Hn * Dn * Ln * 2); // g     [B,H,D,L] 8.4MB
  u16*  yT   = (u16*)alloc((size_t)Bn * Ln * CIn * 2);     // attn out        8.4MB
  u16*  wy   = (u16*)alloc((size_t)Bn * Cn * Ln * 2);      // pre-BN bf16     8.4MB
  float* st  = (float*)alloc(2 * Cn * 4);                  // BN sum/sumsq
  if (ws_size < off) return;  // ~53 MB required

  k_misc<<<dim3(64, 16, 5), 256, 0, stream>>>(x, g_w, t_w, p_w, w_w, xT, Wcat, Ww, st);
  k_proj<<<dim3(16, 12, 4), 256, 0, stream>>>(Wcat, xT, t_b, p_b, g_b, Qb, Kb, Vt);
  k_attn<<<dim3(16, 8, 4), 512, 0, stream>>>(Qb, Kb, Vt, yT);
  k_wgemm<<<dim3(16, 8, 4), 256, 0, stream>>>(Ww, yT, w_b, wy, st);
  k_bn<<<dim3(2048), 256, 0, stream>>>(wy, st, gam, bet, out);
}

// Round 3
// 182.785 us; speedup vs baseline: 1.0332x; 1.0283x over previous
//
#include <hip/hip_runtime.h>

// Problem constants (match reference)
constexpr int Bn = 4, Cn = 512, Ln = 2048, CIn = 512, Hn = 8, Dn = 64;
constexpr int COn = 3 * CIn;  // 1536 stacked output channels: [theta; phi; g]

typedef unsigned short u16;
typedef unsigned int u32;
typedef __attribute__((ext_vector_type(2))) unsigned int u32x2;
typedef __attribute__((ext_vector_type(8))) short bfrag;   // 8 x bf16 (4 VGPRs)
typedef __attribute__((ext_vector_type(4))) float facc;    // 4 x f32 acc
typedef __attribute__((ext_vector_type(16))) float facc16; // 16 x f32 acc (32x32 MFMA)

// 1/sqrt(D) * log2(e): folded into theta weights/bias so QK^T lands in log2 domain
#define SCF 0.180336879f

__device__ __forceinline__ facc mfma16(bfrag a, bfrag b, facc c) {
  return __builtin_amdgcn_mfma_f32_16x16x32_bf16(a, b, c, 0, 0, 0);
}

__device__ __forceinline__ facc16 mfma32(bfrag a, bfrag b, facc16 c) {
  return __builtin_amdgcn_mfma_f32_32x32x16_bf16(a, b, c, 0, 0, 0);
}

__device__ __forceinline__ void async16(const void* g, void* l) {
  __builtin_amdgcn_global_load_lds((const __attribute__((address_space(1))) void*)g,
                                   (__attribute__((address_space(3))) void*)l, 16, 0, 0);
}

__device__ __forceinline__ u16 f2bf(float x) {  // RNE float->bf16
  union { float f; u32 u; } v; v.f = x;
  u32 r = v.u + 0x7FFFu + ((v.u >> 16) & 1u);
  return (u16)(r >> 16);
}

__device__ __forceinline__ u16 f2bf_fast(float x) {  // round-half-up, 2 ops
  union { float f; u32 u; } v; v.f = x;
  return (u16)((v.u + 0x8000u) >> 16);
}

// pack 2 floats -> bf16x2 in one u32: 2 round-adds + 1 v_perm
__device__ __forceinline__ u32 pkbf(float lof, float hif) {
  union { float f; u32 u; } a, b; a.f = lof; b.f = hif;
  return __builtin_amdgcn_perm(b.u + 0x8000u, a.u + 0x8000u, 0x07060302u);
}

// RNE pack via HW instruction: 1 op per 2 floats (dst.lo=bf16(a), dst.hi=bf16(b))
__device__ __forceinline__ u32 cvtpk(float a, float b) {
  u32 r;
  asm("v_cvt_pk_bf16_f32 %0, %1, %2" : "=v"(r) : "v"(a), "v"(b));
  return r;
}

__device__ __forceinline__ float bflo(u32 u) { return __uint_as_float(u << 16); }
__device__ __forceinline__ float bfhi(u32 u) { return __uint_as_float(u & 0xFFFF0000u); }

// Swizzled frag read for row-stride-64-u16 (128B) tiles: granule gi (16B units)
// of row `row` lives at position gi ^ (row&7). Conflict-free b128 reads.
__device__ __forceinline__ bfrag fr8(const u16* base, int row, int gi) {
  return *(const bfrag*)&base[row * 64 + ((gi ^ (row & 7)) * 8)];
}

// ------- kernel 1: fused weights->bf16 + BN-stat zero + x transpose -------
// grid (64,16,5): z<4 -> xpose batch z; z==4 -> weight convert (1024 blocks).
__global__ void k_misc(const float* __restrict__ x, const float* __restrict__ gw,
                       const float* __restrict__ tw, const float* __restrict__ pw,
                       const float* __restrict__ ww, u16* __restrict__ xT,
                       u16* __restrict__ Wcat, u16* __restrict__ Ww,
                       float* __restrict__ stats) {
  int b = blockIdx.z;
  if (b == 4) {  // weight convert path
    int i = (blockIdx.y * 64 + blockIdx.x) * 256 + threadIdx.x;
    if (i < CIn * Cn) {
      Wcat[i]                = f2bf(tw[i] * SCF);  // theta (Q), pre-scaled
      Wcat[CIn * Cn + i]     = f2bf(pw[i]);        // phi   (K)
      Wcat[2 * CIn * Cn + i] = f2bf(gw[i]);        // g     (V)
      Ww[i]                  = f2bf(ww[i]);
    }
    if (i < 2 * Cn) stats[i] = 0.f;  // d_ws is poisoned each launch
    return;
  }
  __shared__ float tile[32][33];
  int l0 = blockIdx.x * 32, c0 = blockIdx.y * 32;
  int tx = threadIdx.x & 31, ty = threadIdx.x >> 5;
  const float* xb = x + (size_t)b * Cn * Ln;
  for (int k = 0; k < 4; k++)
    tile[ty + k * 8][tx] = xb[(size_t)(c0 + ty + k * 8) * Ln + l0 + tx];
  __syncthreads();
  u16* xtb = xT + (size_t)b * Ln * Cn;
  int cc = (threadIdx.x & 15) * 2, r0 = threadIdx.x >> 4;
  for (int k = 0; k < 2; k++) {
    int ll = r0 + k * 16;
    u32 pk = pkbf(tile[cc][ll], tile[cc + 1][ll]);
    *(u32*)&xtb[(size_t)(l0 + ll) * Cn + c0 + cc] = pk;
  }
}

// ------------- GEMM core: C[128,128] = A[128,K] * Bt[128,K]^T -------------
__device__ __forceinline__ void stage128x32(const u16* g, int K, int k0, u16* lds,
                                            int w, int l) {
  int gsw = ((l & 3) ^ ((l >> 3) & 3)) * 8;
  for (int jj = 0; jj < 2; jj++) {
    int j = w * 2 + jj;
    const u16* ga = g + (size_t)(j * 16 + (l >> 2)) * K + k0 + gsw;
    async16(ga, (char*)lds + j * 1024 + l * 16);
  }
}

// SWAP=1 computes C^T tiles (A-operand = Bt rows) for packed transposed stores.
template <int SWAP>
__device__ __forceinline__ void gemm_core(const u16* A, const u16* Bt, int K,
                                          u16* As, u16* Bs, facc acc[4][4],
                                          int w, int l) {
  int quad = l >> 4, lo = l & 15;
  int mw = (w >> 1) * 64, nw = (w & 1) * 64;
  int rsw = (lo >> 1) & 3;
  for (int k0 = 0; k0 < K; k0 += 32) {
    stage128x32(A, K, k0, As, w, l);
    stage128x32(Bt, K, k0, Bs, w, l);
    __syncthreads();
    bfrag af[4], bfv[4];
    for (int mi = 0; mi < 4; mi++)
      af[mi] = *(const bfrag*)&As[(mw + mi * 16 + lo) * 32 + ((quad ^ rsw) * 8)];
    for (int ni = 0; ni < 4; ni++)
      bfv[ni] = *(const bfrag*)&Bs[(nw + ni * 16 + lo) * 32 + ((quad ^ rsw) * 8)];
    for (int mi = 0; mi < 4; mi++)
      for (int ni = 0; ni < 4; ni++)
        acc[mi][ni] = SWAP ? mfma16(bfv[ni], af[mi], acc[mi][ni])
                           : mfma16(af[mi], bfv[ni], acc[mi][ni]);
    __syncthreads();
  }
}

// 64xK * Bt[128,K]^T variant (for k_wgemm)
__device__ __forceinline__ void gemm_core64(const u16* A, const u16* Bt, int K,
                                            u16* As, u16* Bs, facc acc[2][4],
                                            int w, int l) {
  int quad = l >> 4, lo = l & 15;
  int mw = (w >> 1) * 32, nw = (w & 1) * 64;
  int rsw = (lo >> 1) & 3;
  int gsw = ((l & 3) ^ ((l >> 3) & 3)) * 8;
  for (int k0 = 0; k0 < K; k0 += 32) {
    async16(A + (size_t)(w * 16 + (l >> 2)) * K + k0 + gsw, (char*)As + w * 1024 + l * 16);
    stage128x32(Bt, K, k0, Bs, w, l);
    __syncthreads();
    bfrag af[2], bfv[4];
    for (int mi = 0; mi < 2; mi++)
      af[mi] = *(const bfrag*)&As[(mw + mi * 16 + lo) * 32 + ((quad ^ rsw) * 8)];
    for (int ni = 0; ni < 4; ni++)
      bfv[ni] = *(const bfrag*)&Bs[(nw + ni * 16 + lo) * 32 + ((quad ^ rsw) * 8)];
    for (int mi = 0; mi < 2; mi++)
      for (int ni = 0; ni < 4; ni++)
        acc[mi][ni] = mfma16(af[mi], bfv[ni], acc[mi][ni]);
    __syncthreads();
  }
}

// ---------------- kernel 2: fused projection GEMM + head-split epilogue ----------------
__global__ __launch_bounds__(256) void k_proj(
    const u16* __restrict__ Wcat, const u16* __restrict__ xT,
    const float* __restrict__ tb, const float* __restrict__ pb,
    const float* __restrict__ gb, u16* __restrict__ Q, u16* __restrict__ Kb,
    u16* __restrict__ Vt) {
  __shared__ __align__(16) u16 As[128 * 32];
  __shared__ __align__(16) u16 Bs[128 * 32];
  int w = threadIdx.x >> 6, l = threadIdx.x & 63;
  int quad = l >> 4, lo = l & 15;
  int m0 = blockIdx.y * 128, n0 = blockIdx.x * 128, b = blockIdx.z;
  int chunk = m0 >> 9;  // 128-tiles never straddle 512-row chunks
  facc acc[4][4] = {};
  const u16* Ap = Wcat + (size_t)m0 * Cn;
  const u16* Bp = xT + ((size_t)b * Ln + n0) * Cn;
  int mw = (w >> 1) * 64, nw = (w & 1) * 64;
  if (chunk < 2) {
    gemm_core<0>(Ap, Bp, Cn, As, Bs, acc, w, l);
    const float* bias = (chunk == 0) ? tb : pb;
    float bs = (chunk == 0) ? SCF : 1.0f;
    for (int mi = 0; mi < 4; mi++) {
      int mo = (m0 + mw + mi * 16) & 511;
      int hh = mo >> 6;
      int db = (mo & 63) + quad * 4;
      int bi = mo + quad * 4;
      u16* dst0 = ((chunk == 0) ? Q : Kb) + (size_t)(b * Hn + hh) * Ln * 64 + db;
      float b0 = bias[bi] * bs, b1 = bias[bi + 1] * bs;
      float b2 = bias[bi + 2] * bs, b3 = bias[bi + 3] * bs;
      for (int ni = 0; ni < 4; ni++) {
        int lcol = n0 + nw + ni * 16 + lo;
        facc a = acc[mi][ni];
        uint2 pk;
        pk.x = pkbf(a[0] + b0, a[1] + b1);
        pk.y = pkbf(a[2] + b2, a[3] + b3);
        *(uint2*)(dst0 + (size_t)lcol * 64) = pk;
      }
    }
  } else {  // g -> Vt [B,H,D,L], transposed accumulation, packed-l stores
    gemm_core<1>(Ap, Bp, Cn, As, Bs, acc, w, l);
    for (int mi = 0; mi < 4; mi++) {
      int ch = (m0 + mw + mi * 16 + lo) & 511;  // channel per lane
      int hh = ch >> 6, d = ch & 63;
      float bias = gb[ch];
      u16* dst0 = Vt + ((size_t)(b * Hn + hh) * Dn + d) * Ln;
      for (int ni = 0; ni < 4; ni++) {
        int l0 = n0 + nw + ni * 16 + quad * 4;  // 4 consecutive l in acc regs
        facc a = acc[mi][ni];
        uint2 pk;
        pk.x = pkbf(a[0] + bias, a[1] + bias);
        pk.y = pkbf(a[2] + bias, a[3] + bias);
        *(uint2*)(dst0 + l0) = pk;
      }
    }
  }
}

// ---------------- kernel 3: flash attention, 32x32 MFMA, in-register P ----------------
// R10 (= R9 fixed): swapped QK^T on 32x32x16 puts a full q-column per lane
// (C/D: col=lane&31=q, row=kpos); P moves to the PV B-operand entirely in
// registers via v_cvt_pk_bf16_f32 + v_permlane32_swap (T12). Swap semantics
// (verified against T12 recipe): new_dst=(dst.lo,src.lo), new_src=(dst.hi,
// src.hi) across the lane<32/lane>=32 split. R9 had the operand order
// inverted and used raw asm (possible assemble failure -> container death);
// now uses __builtin_amdgcn_permlane32_swap.
// 8 waves = 4 q-waves x 2 t-groups; K/V staged in 128-kpos pairs -> one
// barrier (and one vmcnt drain) per TWO tiles. No P LDS traffic at all.
__global__ __launch_bounds__(512, 4) void k_attn(
    const u16* __restrict__ Q, const u16* __restrict__ Kb,
    const u16* __restrict__ Vt, u16* __restrict__ yT) {
  // K pairs [2][8192] | V pairs [2][8192]  (u16) = 64KB. Q staged into K pair 1.
  __shared__ __align__(16) u16 lds[32768];
  int w = threadIdx.x >> 6, l = threadIdx.x & 63;  // w in 0..7
  int hi = l >> 5, lo5 = l & 31;
  int qw = w & 3, tg = w >> 2;  // q-wave, t-group (tiles t%2==tg)
  int q0 = blockIdx.x * 128, h = blockIdx.y, b = blockIdx.z;
  size_t bh = (size_t)b * Hn + h;
  const u16* Qg = Q + bh * Ln * 64;
  const u16* Kg = Kb + bh * Ln * 64;
  const u16* Vg = Vt + bh * (size_t)Dn * Ln;

  int rin = l >> 3;
  int gg = ((l & 7) ^ rin) * 8;

  // startup: Q -> K pair 1; K/V tiles {0,1} -> pair 0
  for (int jj = 0; jj < 2; jj++) {
    int j = w * 2 + jj;  // j in 0..15: 8 rows each of the 128-row pair
    async16(Qg + (size_t)(q0 + j * 8 + rin) * 64 + gg,
            (char*)lds + 16384 + j * 1024 + l * 16);
    async16(Kg + (size_t)(j * 8 + rin) * 64 + gg,
            (char*)lds + j * 1024 + l * 16);
    async16(Vg + (size_t)((j & 7) * 8 + rin) * Ln + (j >> 3) * 64 + gg,
            (char*)lds + 32768 + j * 1024 + l * 16);
  }
  __syncthreads();
  // hoist Q frags: lane holds Q[q = qw*32+lo5][d = c*16 + hi*8 + e]
  bfrag qf[4];
  int ql = qw * 32 + lo5;
  for (int c = 0; c < 4; c++)
    qf[c] = fr8(lds + 8192 + (ql >> 6) * 4096, ql & 63, c * 2 + hi);
  __syncthreads();  // protect Q reads from super-iter 0's pair-1 prefetch

  facc16 o[2] = {};  // O^T[d = dh*32 + (reg&3)+8*(reg>>2)+4*hi][q = qw*32+lo5]
  float l_i = 0.f;

  for (int s = 0; s < 16; s++) {  // super-iter: 2 tiles (128 kpos)
    if (s < 15) {  // prefetch next pair
      int pp = (s + 1) & 1;
      int kbase = (s + 1) * 128;
      for (int jj = 0; jj < 2; jj++) {
        int j = w * 2 + jj;
        async16(Kg + (size_t)(kbase + j * 8 + rin) * 64 + gg,
                (char*)lds + pp * 16384 + j * 1024 + l * 16);
        async16(Vg + (size_t)((j & 7) * 8 + rin) * Ln + kbase + (j >> 3) * 64 + gg,
                (char*)lds + 32768 + pp * 16384 + j * 1024 + l * 16);
      }
    }
    const u16* Kc = lds + (s & 1) * 8192 + tg * 4096;          // my tile of the pair
    const u16* Vc = lds + 16384 + (s & 1) * 8192 + tg * 4096;
    for (int kh = 0; kh < 2; kh++) {  // two 32-kpos halves of the 64-kpos tile
      facc16 sA = {};
      for (int c = 0; c < 4; c++) {
        bfrag kf = fr8(Kc, kh * 32 + lo5, c * 2 + hi);  // K[kpos][d-slice]
        sA = mfma32(kf, qf[c], sA);  // S[kpos][q], log2 domain (SCF folded)
      }
      float p[16];
#pragma unroll
      for (int r = 0; r < 16; r++) p[r] = __builtin_amdgcn_exp2f(sA[r]);
      l_i += (((p[0] + p[1]) + (p[2] + p[3])) + ((p[4] + p[5]) + (p[6] + p[7]))) +
             (((p[8] + p[9]) + (p[10] + p[11])) + ((p[12] + p[13]) + (p[14] + p[15])));
      // pack + in-register exchange: pb frag for PV mfma m = kh*2+m2.
      // X = quads {0,2} pair, Y = quads {1,3} pair of the m2-block;
      // permlane32_swap(X,Y) -> r0=(X.lo,Y.lo)=word p2, r1=(X.hi,Y.hi)=word 2+p2.
#pragma unroll
      for (int m2 = 0; m2 < 2; m2++) {
        union { u32 u[4]; bfrag f; } pbu;
#pragma unroll
        for (int p2 = 0; p2 < 2; p2++) {
          u32 x = cvtpk(p[8 * m2 + 2 * p2], p[8 * m2 + 2 * p2 + 1]);
          u32 y = cvtpk(p[8 * m2 + 4 + 2 * p2], p[8 * m2 + 4 + 2 * p2 + 1]);
          u32x2 r = __builtin_amdgcn_permlane32_swap(x, y, false, false);
          pbu.u[p2] = r[0];
          pbu.u[2 + p2] = r[1];
        }
        int m = kh * 2 + m2;
        for (int dh = 0; dh < 2; dh++) {
          bfrag vf = fr8(Vc, dh * 32 + lo5, m * 2 + hi);  // V^T[d][kpos-slice]
          o[dh] = mfma32(vf, pbu.f, o[dh]);
        }
      }
    }
    __syncthreads();
  }

  // epilogue: cross-group combine (group1 -> LDS f32, group0 sums+normalizes)
  l_i += __shfl_xor(l_i, 32);
  float* fp = (float*)lds;
  int slot = (qw * 64 + l) * 36;  // 36-f32 stride: 16B-aligned blocks
  if (tg == 1) {
#pragma unroll
    for (int dh = 0; dh < 2; dh++)
#pragma unroll
      for (int r = 0; r < 16; r++) fp[slot + dh * 16 + r] = o[dh][r];
    fp[slot + 32] = l_i;
  }
  __syncthreads();
  if (tg == 0) {
    float inv = 1.0f / (l_i + fp[slot + 32]);
    int q = q0 + qw * 32 + lo5;
    u16* dst = yT + ((size_t)b * Ln + q) * CIn + h * 64;
#pragma unroll
    for (int dh = 0; dh < 2; dh++)
#pragma unroll
      for (int rq = 0; rq < 4; rq++) {
        float v0 = (o[dh][rq * 4 + 0] + fp[slot + dh * 16 + rq * 4 + 0]) * inv;
        float v1 = (o[dh][rq * 4 + 1] + fp[slot + dh * 16 + rq * 4 + 1]) * inv;
        float v2 = (o[dh][rq * 4 + 2] + fp[slot + dh * 16 + rq * 4 + 2]) * inv;
        float v3 = (o[dh][rq * 4 + 3] + fp[slot + dh * 16 + rq * 4 + 3]) * inv;
        uint2 pk;
        pk.x = pkbf(v0, v1);
        pk.y = pkbf(v2, v3);
        *(uint2*)(dst + dh * 32 + rq * 8 + 4 * hi) = pk;
      }
  }
}

// ---------------- kernel 4: W GEMM (64x128 tiles) + BN statistics ----------------
__global__ __launch_bounds__(256) void k_wgemm(
    const u16* __restrict__ Ww, const u16* __restrict__ yT,
    const float* __restrict__ wb, u16* __restrict__ wy,
    float* __restrict__ stats) {
  __shared__ __align__(16) u16 As[64 * 32];
  __shared__ __align__(16) u16 Bs[128 * 32];
  int w = threadIdx.x >> 6, l = threadIdx.x & 63;
  int quad = l >> 4, lo = l & 15;
  int m0 = blockIdx.y * 64, n0 = blockIdx.x * 128, b = blockIdx.z;
  facc acc[2][4] = {};
  gemm_core64(Ww + (size_t)m0 * CIn, yT + ((size_t)b * Ln + n0) * CIn, CIn, As, Bs, acc, w, l);
  int mw = (w >> 1) * 32, nw = (w & 1) * 64;
  for (int mi = 0; mi < 2; mi++) {
    int cb = m0 + mw + mi * 16 + quad * 4;
    for (int r = 0; r < 4; r++) {
      float bias = wb[cb + r];
      float s = 0.f, q = 0.f;
      for (int ni = 0; ni < 4; ni++) {
        float v = acc[mi][ni][r] + bias;
        wy[((size_t)b * Cn + cb + r) * Ln + n0 + nw + ni * 16 + lo] = f2bf_fast(v);
        s += v; q += v * v;  // stats from fp32 pre-round values
      }
      for (int mask = 1; mask < 16; mask <<= 1) {
        s += __shfl_xor(s, mask);
        q += __shfl_xor(q, mask);
      }
      if (lo == 0) {
        atomicAdd(&stats[cb + r], s);
        atomicAdd(&stats[Cn + cb + r], q);
      }
    }
  }
}

// ---------------- kernel 5: BN apply (bf16 in, f32 out) ----------------
__global__ void k_bn(const u16* __restrict__ wy, const float* __restrict__ stats,
                     const float* __restrict__ gam, const float* __restrict__ bet,
                     float* __restrict__ out) {
  int i = blockIdx.x * 256 + threadIdx.x;
  size_t idx = (size_t)i * 8;
  int c = (int)((idx >> 11) & (Cn - 1));  // [B,C,L], L=2^11
  const float invN = 1.f / (Bn * Ln);
  float mean = stats[c] * invN;
  float var = stats[Cn + c] * invN - mean * mean;
  float scl = gam[c] * rsqrtf(var + 1e-5f);
  float sh = bet[c] - mean * scl;
  uint4 v = *(const uint4*)(wy + idx);
  float4 o0, o1;
  o0.x = bflo(v.x) * scl + sh; o0.y = bfhi(v.x) * scl + sh;
  o0.z = bflo(v.y) * scl + sh; o0.w = bfhi(v.y) * scl + sh;
  o1.x = bflo(v.z) * scl + sh; o1.y = bfhi(v.z) * scl + sh;
  o1.z = bflo(v.w) * scl + sh; o1.w = bfhi(v.w) * scl + sh;
  *(float4*)(out + idx) = o0;
  *(float4*)(out + idx + 4) = o1;
}

extern "C" void kernel_launch(void* const* d_in, const int* in_sizes, int n_in,
                              void* d_out, int out_size, void* d_ws, size_t ws_size,
                              hipStream_t stream) {
  const float* x   = (const float*)d_in[0];
  const float* g_w = (const float*)d_in[1];
  const float* g_b = (const float*)d_in[2];
  const float* t_w = (const float*)d_in[3];
  const float* t_b = (const float*)d_in[4];
  const float* p_w = (const float*)d_in[5];
  const float* p_b = (const float*)d_in[6];
  const float* w_w = (const float*)d_in[7];
  const float* w_b = (const float*)d_in[8];
  const float* gam = (const float*)d_in[9];
  const float* bet = (const float*)d_in[10];
  float* out = (float*)d_out;

  char* ws = (char*)d_ws;
  size_t off = 0;
  auto alloc = [&](size_t bytes) {
    char* p = ws + off; off += (bytes + 255) & ~(size_t)255; return p;
  };
  u16*  xT   = (u16*)alloc((size_t)Bn * Ln * Cn * 2);      // x^T bf16        8.4MB
  u16*  Wcat = (u16*)alloc((size_t)COn * Cn * 2);          // [theta;phi;g]   1.6MB
  u16*  Ww   = (u16*)alloc((size_t)Cn * CIn * 2);          // w_w bf16        0.5MB
  u16*  Qb   = (u16*)alloc((size_t)Bn * Hn * Ln * Dn * 2); // theta [B,H,L,D] 8.4MB
  u16*  Kb   = (u16*)alloc((size_t)Bn * Hn * Ln * Dn * 2); // phi   [B,H,L,D] 8.4MB
  u16*  Vt   = (u16*)alloc((size_t)Bn * Hn * Dn * Ln * 2); // g     [B,H,D,L] 8.4MB
  u16*  yT   = (u16*)alloc((size_t)Bn * Ln * CIn * 2);     // attn out        8.4MB
  u16*  wy   = (u16*)alloc((size_t)Bn * Cn * Ln * 2);      // pre-BN bf16     8.4MB
  float* st  = (float*)alloc(2 * Cn * 4);                  // BN sum/sumsq
  if (ws_size < off) return;  // ~53 MB required

  k_misc<<<dim3(64, 16, 5), 256, 0, stream>>>(x, g_w, t_w, p_w, w_w, xT, Wcat, Ww, st);
  k_proj<<<dim3(16, 12, 4), 256, 0, stream>>>(Wcat, xT, t_b, p_b, g_b, Qb, Kb, Vt);
  k_attn<<<dim3(16, 8, 4), 512, 0, stream>>>(Qb, Kb, Vt, yT);
  k_wgemm<<<dim3(16, 8, 4), 256, 0, stream>>>(Ww, yT, w_b, wy, st);
  k_bn<<<dim3(2048), 256, 0, stream>>>(wy, st, gam, bet, out);
}

// Round 4
// 173.869 us; speedup vs baseline: 1.0862x; 1.0513x over previous
//
#include <hip/hip_runtime.h>

// Problem constants (match reference)
constexpr int Bn = 4, Cn = 512, Ln = 2048, CIn = 512, Hn = 8, Dn = 64;
constexpr int COn = 3 * CIn;  // 1536 stacked output channels: [theta; phi; g]

typedef unsigned short u16;
typedef unsigned int u32;
typedef __attribute__((ext_vector_type(2))) unsigned int u32x2;
typedef __attribute__((ext_vector_type(8))) short bfrag;   // 8 x bf16 (4 VGPRs)
typedef __attribute__((ext_vector_type(4))) float facc;    // 4 x f32 acc
typedef __attribute__((ext_vector_type(16))) float facc16; // 16 x f32 acc (32x32 MFMA)

// 1/sqrt(D) * log2(e): folded into theta weights/bias so QK^T lands in log2 domain
#define SCF 0.180336879f

__device__ __forceinline__ facc mfma16(bfrag a, bfrag b, facc c) {
  return __builtin_amdgcn_mfma_f32_16x16x32_bf16(a, b, c, 0, 0, 0);
}

__device__ __forceinline__ facc16 mfma32(bfrag a, bfrag b, facc16 c) {
  return __builtin_amdgcn_mfma_f32_32x32x16_bf16(a, b, c, 0, 0, 0);
}

__device__ __forceinline__ void async16(const void* g, void* l) {
  __builtin_amdgcn_global_load_lds((const __attribute__((address_space(1))) void*)g,
                                   (__attribute__((address_space(3))) void*)l, 16, 0, 0);
}

__device__ __forceinline__ u16 f2bf(float x) {  // RNE float->bf16
  union { float f; u32 u; } v; v.f = x;
  u32 r = v.u + 0x7FFFu + ((v.u >> 16) & 1u);
  return (u16)(r >> 16);
}

__device__ __forceinline__ u16 f2bf_fast(float x) {  // round-half-up, 2 ops
  union { float f; u32 u; } v; v.f = x;
  return (u16)((v.u + 0x8000u) >> 16);
}

// pack 2 floats -> bf16x2 in one u32: 2 round-adds + 1 v_perm
__device__ __forceinline__ u32 pkbf(float lof, float hif) {
  union { float f; u32 u; } a, b; a.f = lof; b.f = hif;
  return __builtin_amdgcn_perm(b.u + 0x8000u, a.u + 0x8000u, 0x07060302u);
}

// RNE pack via HW instruction: 1 op per 2 floats (dst.lo=bf16(a), dst.hi=bf16(b))
__device__ __forceinline__ u32 cvtpk(float a, float b) {
  u32 r;
  asm("v_cvt_pk_bf16_f32 %0, %1, %2" : "=v"(r) : "v"(a), "v"(b));
  return r;
}

__device__ __forceinline__ float bflo(u32 u) { return __uint_as_float(u << 16); }
__device__ __forceinline__ float bfhi(u32 u) { return __uint_as_float(u & 0xFFFF0000u); }

// Swizzled frag read for row-stride-64-u16 (128B) tiles: granule gi (16B units)
// of row `row` lives at position gi ^ (row&7). Conflict-free b128 reads.
__device__ __forceinline__ bfrag fr8(const u16* base, int row, int gi) {
  return *(const bfrag*)&base[row * 64 + ((gi ^ (row & 7)) * 8)];
}

// ------- kernel 1: fused weights->bf16 + BN-stat zero + x transpose -------
// grid (64,16,5): z<4 -> xpose batch z; z==4 -> weight convert (1024 blocks).
__global__ void k_misc(const float* __restrict__ x, const float* __restrict__ gw,
                       const float* __restrict__ tw, const float* __restrict__ pw,
                       const float* __restrict__ ww, u16* __restrict__ xT,
                       u16* __restrict__ Wcat, u16* __restrict__ Ww,
                       float* __restrict__ stats) {
  int b = blockIdx.z;
  if (b == 4) {  // weight convert path
    int i = (blockIdx.y * 64 + blockIdx.x) * 256 + threadIdx.x;
    if (i < CIn * Cn) {
      Wcat[i]                = f2bf(tw[i] * SCF);  // theta (Q), pre-scaled
      Wcat[CIn * Cn + i]     = f2bf(pw[i]);        // phi   (K)
      Wcat[2 * CIn * Cn + i] = f2bf(gw[i]);        // g     (V)
      Ww[i]                  = f2bf(ww[i]);
    }
    if (i < 2 * Cn) stats[i] = 0.f;  // d_ws is poisoned each launch
    return;
  }
  __shared__ float tile[32][33];
  int l0 = blockIdx.x * 32, c0 = blockIdx.y * 32;
  int tx = threadIdx.x & 31, ty = threadIdx.x >> 5;
  const float* xb = x + (size_t)b * Cn * Ln;
  for (int k = 0; k < 4; k++)
    tile[ty + k * 8][tx] = xb[(size_t)(c0 + ty + k * 8) * Ln + l0 + tx];
  __syncthreads();
  u16* xtb = xT + (size_t)b * Ln * Cn;
  int cc = (threadIdx.x & 15) * 2, r0 = threadIdx.x >> 4;
  for (int k = 0; k < 2; k++) {
    int ll = r0 + k * 16;
    u32 pk = pkbf(tile[cc][ll], tile[cc + 1][ll]);
    *(u32*)&xtb[(size_t)(l0 + ll) * Cn + c0 + cc] = pk;
  }
}

// ------------- GEMM core: C[128,128] = A[128,K] * Bt[128,K]^T -------------
__device__ __forceinline__ void stage128x32(const u16* g, int K, int k0, u16* lds,
                                            int w, int l) {
  int gsw = ((l & 3) ^ ((l >> 3) & 3)) * 8;
  for (int jj = 0; jj < 2; jj++) {
    int j = w * 2 + jj;
    const u16* ga = g + (size_t)(j * 16 + (l >> 2)) * K + k0 + gsw;
    async16(ga, (char*)lds + j * 1024 + l * 16);
  }
}

// SWAP=1 computes C^T tiles (A-operand = Bt rows) for packed transposed stores.
template <int SWAP>
__device__ __forceinline__ void gemm_core(const u16* A, const u16* Bt, int K,
                                          u16* As, u16* Bs, facc acc[4][4],
                                          int w, int l) {
  int quad = l >> 4, lo = l & 15;
  int mw = (w >> 1) * 64, nw = (w & 1) * 64;
  int rsw = (lo >> 1) & 3;
  for (int k0 = 0; k0 < K; k0 += 32) {
    stage128x32(A, K, k0, As, w, l);
    stage128x32(Bt, K, k0, Bs, w, l);
    __syncthreads();
    bfrag af[4], bfv[4];
    for (int mi = 0; mi < 4; mi++)
      af[mi] = *(const bfrag*)&As[(mw + mi * 16 + lo) * 32 + ((quad ^ rsw) * 8)];
    for (int ni = 0; ni < 4; ni++)
      bfv[ni] = *(const bfrag*)&Bs[(nw + ni * 16 + lo) * 32 + ((quad ^ rsw) * 8)];
    for (int mi = 0; mi < 4; mi++)
      for (int ni = 0; ni < 4; ni++)
        acc[mi][ni] = SWAP ? mfma16(bfv[ni], af[mi], acc[mi][ni])
                           : mfma16(af[mi], bfv[ni], acc[mi][ni]);
    __syncthreads();
  }
}

// 64xK * Bt[128,K]^T variant (for k_wgemm)
__device__ __forceinline__ void gemm_core64(const u16* A, const u16* Bt, int K,
                                            u16* As, u16* Bs, facc acc[2][4],
                                            int w, int l) {
  int quad = l >> 4, lo = l & 15;
  int mw = (w >> 1) * 32, nw = (w & 1) * 64;
  int rsw = (lo >> 1) & 3;
  int gsw = ((l & 3) ^ ((l >> 3) & 3)) * 8;
  for (int k0 = 0; k0 < K; k0 += 32) {
    async16(A + (size_t)(w * 16 + (l >> 2)) * K + k0 + gsw, (char*)As + w * 1024 + l * 16);
    stage128x32(Bt, K, k0, Bs, w, l);
    __syncthreads();
    bfrag af[2], bfv[4];
    for (int mi = 0; mi < 2; mi++)
      af[mi] = *(const bfrag*)&As[(mw + mi * 16 + lo) * 32 + ((quad ^ rsw) * 8)];
    for (int ni = 0; ni < 4; ni++)
      bfv[ni] = *(const bfrag*)&Bs[(nw + ni * 16 + lo) * 32 + ((quad ^ rsw) * 8)];
    for (int mi = 0; mi < 2; mi++)
      for (int ni = 0; ni < 4; ni++)
        acc[mi][ni] = mfma16(af[mi], bfv[ni], acc[mi][ni]);
    __syncthreads();
  }
}

// ---------------- kernel 2: fused projection GEMM + head-split epilogue ----------------
__global__ __launch_bounds__(256) void k_proj(
    const u16* __restrict__ Wcat, const u16* __restrict__ xT,
    const float* __restrict__ tb, const float* __restrict__ pb,
    const float* __restrict__ gb, u16* __restrict__ Q, u16* __restrict__ Kb,
    u16* __restrict__ Vt) {
  __shared__ __align__(16) u16 As[128 * 32];
  __shared__ __align__(16) u16 Bs[128 * 32];
  int w = threadIdx.x >> 6, l = threadIdx.x & 63;
  int quad = l >> 4, lo = l & 15;
  int m0 = blockIdx.y * 128, n0 = blockIdx.x * 128, b = blockIdx.z;
  int chunk = m0 >> 9;  // 128-tiles never straddle 512-row chunks
  facc acc[4][4] = {};
  const u16* Ap = Wcat + (size_t)m0 * Cn;
  const u16* Bp = xT + ((size_t)b * Ln + n0) * Cn;
  int mw = (w >> 1) * 64, nw = (w & 1) * 64;
  if (chunk < 2) {
    gemm_core<0>(Ap, Bp, Cn, As, Bs, acc, w, l);
    const float* bias = (chunk == 0) ? tb : pb;
    float bs = (chunk == 0) ? SCF : 1.0f;
    for (int mi = 0; mi < 4; mi++) {
      int mo = (m0 + mw + mi * 16) & 511;
      int hh = mo >> 6;
      int db = (mo & 63) + quad * 4;
      int bi = mo + quad * 4;
      u16* dst0 = ((chunk == 0) ? Q : Kb) + (size_t)(b * Hn + hh) * Ln * 64 + db;
      float b0 = bias[bi] * bs, b1 = bias[bi + 1] * bs;
      float b2 = bias[bi + 2] * bs, b3 = bias[bi + 3] * bs;
      for (int ni = 0; ni < 4; ni++) {
        int lcol = n0 + nw + ni * 16 + lo;
        facc a = acc[mi][ni];
        uint2 pk;
        pk.x = pkbf(a[0] + b0, a[1] + b1);
        pk.y = pkbf(a[2] + b2, a[3] + b3);
        *(uint2*)(dst0 + (size_t)lcol * 64) = pk;
      }
    }
  } else {  // g -> Vt [B,H,D,L], transposed accumulation, packed-l stores
    gemm_core<1>(Ap, Bp, Cn, As, Bs, acc, w, l);
    for (int mi = 0; mi < 4; mi++) {
      int ch = (m0 + mw + mi * 16 + lo) & 511;  // channel per lane
      int hh = ch >> 6, d = ch & 63;
      float bias = gb[ch];
      u16* dst0 = Vt + ((size_t)(b * Hn + hh) * Dn + d) * Ln;
      for (int ni = 0; ni < 4; ni++) {
        int l0 = n0 + nw + ni * 16 + quad * 4;  // 4 consecutive l in acc regs
        facc a = acc[mi][ni];
        uint2 pk;
        pk.x = pkbf(a[0] + bias, a[1] + bias);
        pk.y = pkbf(a[2] + bias, a[3] + bias);
        *(uint2*)(dst0 + l0) = pk;
      }
    }
  }
}

// ---------------- kernel 3: flash attention, 32x32 MFMA, 64 q/wave ----------------
// R11: R3's counters decompose per-CU per-super-iter as MFMA 2048cy (=31%
// MfmaUtil, exact), VALU ~2600cy (=40%), LDS ~4630cy (reads 3072 + conflict
// 1046 + staging 512) -> LDS-read-throughput-bound: all 4 q-waves per t-group
// re-read the SAME K/V frags. Fix: 64 q per wave (two 32-q column sets share
// each kf/vf read) -> per-CU LDS reads halve; MFMA/VALU/traffic unchanged.
// 4 waves (256 thr) = 2 q-waves x 2 t-groups; same 64KB LDS, same swizzles,
// same in-register P (cvt_pk_bf16 + permlane32_swap); per-lane numerics
// bit-identical to R3.
__global__ __launch_bounds__(256, 2) void k_attn(
    const u16* __restrict__ Q, const u16* __restrict__ Kb,
    const u16* __restrict__ Vt, u16* __restrict__ yT) {
  // K pairs [2][8192] | V pairs [2][8192]  (u16) = 64KB. Q staged into K pair 1.
  __shared__ __align__(16) u16 lds[32768];
  int w = threadIdx.x >> 6, l = threadIdx.x & 63;  // w in 0..3
  int hi = l >> 5, lo5 = l & 31;
  int qw = w & 1, tg = w >> 1;  // q-wave (64 q each), t-group (tiles t%2==tg)
  int q0 = blockIdx.x * 128, h = blockIdx.y, b = blockIdx.z;
  size_t bh = (size_t)b * Hn + h;
  const u16* Qg = Q + bh * Ln * 64;
  const u16* Kg = Kb + bh * Ln * 64;
  const u16* Vg = Vt + bh * (size_t)Dn * Ln;

  int rin = l >> 3;
  int gg = ((l & 7) ^ rin) * 8;

  // startup: Q -> K pair 1; K/V tiles {0,1} -> pair 0. 4 waves x 4 groups.
  for (int jj = 0; jj < 4; jj++) {
    int j = w * 4 + jj;  // j in 0..15: 8 rows each of the 128-row pair
    async16(Qg + (size_t)(q0 + j * 8 + rin) * 64 + gg,
            (char*)lds + 16384 + j * 1024 + l * 16);
    async16(Kg + (size_t)(j * 8 + rin) * 64 + gg,
            (char*)lds + j * 1024 + l * 16);
    async16(Vg + (size_t)((j & 7) * 8 + rin) * Ln + (j >> 3) * 64 + gg,
            (char*)lds + 32768 + j * 1024 + l * 16);
  }
  __syncthreads();
  // hoist Q frags: qf[qs][c] = Q[q = qw*64 + qs*32 + lo5][d = c*16 + hi*8 + e]
  bfrag qf[2][4];
#pragma unroll
  for (int qs = 0; qs < 2; qs++)
#pragma unroll
    for (int c = 0; c < 4; c++)
      qf[qs][c] = fr8(lds + 8192, qw * 64 + qs * 32 + lo5, c * 2 + hi);
  __syncthreads();  // protect Q reads from super-iter 0's pair-1 prefetch

  facc16 o[2][2] = {};  // [qs][dh]: O^T[d = dh*32+(r&3)+8*(r>>2)+4*hi][q]
  float l_i[2] = {0.f, 0.f};

  for (int s = 0; s < 16; s++) {  // super-iter: 2 tiles (128 kpos)
    if (s < 15) {  // prefetch next pair
      int pp = (s + 1) & 1;
      int kbase = (s + 1) * 128;
      for (int jj = 0; jj < 4; jj++) {
        int j = w * 4 + jj;
        async16(Kg + (size_t)(kbase + j * 8 + rin) * 64 + gg,
                (char*)lds + pp * 16384 + j * 1024 + l * 16);
        async16(Vg + (size_t)((j & 7) * 8 + rin) * Ln + kbase + (j >> 3) * 64 + gg,
                (char*)lds + 32768 + pp * 16384 + j * 1024 + l * 16);
      }
    }
    const u16* Kc = lds + (s & 1) * 8192 + tg * 4096;          // my tile of the pair
    const u16* Vc = lds + 16384 + (s & 1) * 8192 + tg * 4096;
#pragma unroll
    for (int kh = 0; kh < 2; kh++) {  // two 32-kpos halves of the 64-kpos tile
      bfrag kf[4];
#pragma unroll
      for (int c = 0; c < 4; c++) kf[c] = fr8(Kc, kh * 32 + lo5, c * 2 + hi);
      facc16 sA0 = {}, sA1 = {};
#pragma unroll
      for (int c = 0; c < 4; c++) sA0 = mfma32(kf[c], qf[0][c], sA0);
#pragma unroll
      for (int c = 0; c < 4; c++) sA1 = mfma32(kf[c], qf[1][c], sA1);
      // exp + pack + in-register exchange, per q-set
      bfrag pbA[2], pbB[2];
      {
        float p[16];
#pragma unroll
        for (int r = 0; r < 16; r++) p[r] = __builtin_amdgcn_exp2f(sA0[r]);
        l_i[0] += (((p[0] + p[1]) + (p[2] + p[3])) + ((p[4] + p[5]) + (p[6] + p[7]))) +
                  (((p[8] + p[9]) + (p[10] + p[11])) + ((p[12] + p[13]) + (p[14] + p[15])));
#pragma unroll
        for (int m2 = 0; m2 < 2; m2++) {
          union { u32 u[4]; bfrag f; } pbu;
#pragma unroll
          for (int p2 = 0; p2 < 2; p2++) {
            u32 x = cvtpk(p[8 * m2 + 2 * p2], p[8 * m2 + 2 * p2 + 1]);
            u32 y = cvtpk(p[8 * m2 + 4 + 2 * p2], p[8 * m2 + 4 + 2 * p2 + 1]);
            u32x2 r2 = __builtin_amdgcn_permlane32_swap(x, y, false, false);
            pbu.u[p2] = r2[0];
            pbu.u[2 + p2] = r2[1];
          }
          pbA[m2] = pbu.f;
        }
      }
      {
        float p[16];
#pragma unroll
        for (int r = 0; r < 16; r++) p[r] = __builtin_amdgcn_exp2f(sA1[r]);
        l_i[1] += (((p[0] + p[1]) + (p[2] + p[3])) + ((p[4] + p[5]) + (p[6] + p[7]))) +
                  (((p[8] + p[9]) + (p[10] + p[11])) + ((p[12] + p[13]) + (p[14] + p[15])));
#pragma unroll
        for (int m2 = 0; m2 < 2; m2++) {
          union { u32 u[4]; bfrag f; } pbu;
#pragma unroll
          for (int p2 = 0; p2 < 2; p2++) {
            u32 x = cvtpk(p[8 * m2 + 2 * p2], p[8 * m2 + 2 * p2 + 1]);
            u32 y = cvtpk(p[8 * m2 + 4 + 2 * p2], p[8 * m2 + 4 + 2 * p2 + 1]);
            u32x2 r2 = __builtin_amdgcn_permlane32_swap(x, y, false, false);
            pbu.u[p2] = r2[0];
            pbu.u[2 + p2] = r2[1];
          }
          pbB[m2] = pbu.f;
        }
      }
      // PV: each V frag feeds BOTH q-sets (the read-halving lever)
#pragma unroll
      for (int m2 = 0; m2 < 2; m2++) {
        int m = kh * 2 + m2;
#pragma unroll
        for (int dh = 0; dh < 2; dh++) {
          bfrag vf = fr8(Vc, dh * 32 + lo5, m * 2 + hi);  // V^T[d][kpos-slice]
          o[0][dh] = mfma32(vf, pbA[m2], o[0][dh]);
          o[1][dh] = mfma32(vf, pbB[m2], o[1][dh]);
        }
      }
    }
    __syncthreads();
  }

  // epilogue: cross-group combine (group1 -> LDS f32, group0 sums+normalizes)
  l_i[0] += __shfl_xor(l_i[0], 32);
  l_i[1] += __shfl_xor(l_i[1], 32);
  float* fp = (float*)lds;
  int slot = (qw * 64 + l) * 67;  // odd stride: conflict-free f32 columns
  if (tg == 1) {
#pragma unroll
    for (int qs = 0; qs < 2; qs++)
#pragma unroll
      for (int dh = 0; dh < 2; dh++)
#pragma unroll
        for (int r = 0; r < 16; r++) fp[slot + qs * 32 + dh * 16 + r] = o[qs][dh][r];
    fp[slot + 64] = l_i[0];
    fp[slot + 65] = l_i[1];
  }
  __syncthreads();
  if (tg == 0) {
#pragma unroll
    for (int qs = 0; qs < 2; qs++) {
      float inv = 1.0f / (l_i[qs] + fp[slot + 64 + qs]);
      int q = q0 + qw * 64 + qs * 32 + lo5;
      u16* dst = yT + ((size_t)b * Ln + q) * CIn + h * 64;
#pragma unroll
      for (int dh = 0; dh < 2; dh++)
#pragma unroll
        for (int rq = 0; rq < 4; rq++) {
          float v0 = (o[qs][dh][rq * 4 + 0] + fp[slot + qs * 32 + dh * 16 + rq * 4 + 0]) * inv;
          float v1 = (o[qs][dh][rq * 4 + 1] + fp[slot + qs * 32 + dh * 16 + rq * 4 + 1]) * inv;
          float v2 = (o[qs][dh][rq * 4 + 2] + fp[slot + qs * 32 + dh * 16 + rq * 4 + 2]) * inv;
          float v3 = (o[qs][dh][rq * 4 + 3] + fp[slot + qs * 32 + dh * 16 + rq * 4 + 3]) * inv;
          uint2 pk;
          pk.x = pkbf(v0, v1);
          pk.y = pkbf(v2, v3);
          *(uint2*)(dst + dh * 32 + rq * 8 + 4 * hi) = pk;
        }
    }
  }
}

// ---------------- kernel 4: W GEMM (64x128 tiles) + BN statistics ----------------
__global__ __launch_bounds__(256) void k_wgemm(
    const u16* __restrict__ Ww, const u16* __restrict__ yT,
    const float* __restrict__ wb, u16* __restrict__ wy,
    float* __restrict__ stats) {
  __shared__ __align__(16) u16 As[64 * 32];
  __shared__ __align__(16) u16 Bs[128 * 32];
  int w = threadIdx.x >> 6, l = threadIdx.x & 63;
  int quad = l >> 4, lo = l & 15;
  int m0 = blockIdx.y * 64, n0 = blockIdx.x * 128, b = blockIdx.z;
  facc acc[2][4] = {};
  gemm_core64(Ww + (size_t)m0 * CIn, yT + ((size_t)b * Ln + n0) * CIn, CIn, As, Bs, acc, w, l);
  int mw = (w >> 1) * 32, nw = (w & 1) * 64;
  for (int mi = 0; mi < 2; mi++) {
    int cb = m0 + mw + mi * 16 + quad * 4;
    for (int r = 0; r < 4; r++) {
      float bias = wb[cb + r];
      float s = 0.f, q = 0.f;
      for (int ni = 0; ni < 4; ni++) {
        float v = acc[mi][ni][r] + bias;
        wy[((size_t)b * Cn + cb + r) * Ln + n0 + nw + ni * 16 + lo] = f2bf_fast(v);
        s += v; q += v * v;  // stats from fp32 pre-round values
      }
      for (int mask = 1; mask < 16; mask <<= 1) {
        s += __shfl_xor(s, mask);
        q += __shfl_xor(q, mask);
      }
      if (lo == 0) {
        atomicAdd(&stats[cb + r], s);
        atomicAdd(&stats[Cn + cb + r], q);
      }
    }
  }
}

// ---------------- kernel 5: BN apply (bf16 in, f32 out) ----------------
__global__ void k_bn(const u16* __restrict__ wy, const float* __restrict__ stats,
                     const float* __restrict__ gam, const float* __restrict__ bet,
                     float* __restrict__ out) {
  int i = blockIdx.x * 256 + threadIdx.x;
  size_t idx = (size_t)i * 8;
  int c = (int)((idx >> 11) & (Cn - 1));  // [B,C,L], L=2^11
  const float invN = 1.f / (Bn * Ln);
  float mean = stats[c] * invN;
  float var = stats[Cn + c] * invN - mean * mean;
  float scl = gam[c] * rsqrtf(var + 1e-5f);
  float sh = bet[c] - mean * scl;
  uint4 v = *(const uint4*)(wy + idx);
  float4 o0, o1;
  o0.x = bflo(v.x) * scl + sh; o0.y = bfhi(v.x) * scl + sh;
  o0.z = bflo(v.y) * scl + sh; o0.w = bfhi(v.y) * scl + sh;
  o1.x = bflo(v.z) * scl + sh; o1.y = bfhi(v.z) * scl + sh;
  o1.z = bflo(v.w) * scl + sh; o1.w = bfhi(v.w) * scl + sh;
  *(float4*)(out + idx) = o0;
  *(float4*)(out + idx + 4) = o1;
}

extern "C" void kernel_launch(void* const* d_in, const int* in_sizes, int n_in,
                              void* d_out, int out_size, void* d_ws, size_t ws_size,
                              hipStream_t stream) {
  const float* x   = (const float*)d_in[0];
  const float* g_w = (const float*)d_in[1];
  const float* g_b = (const float*)d_in[2];
  const float* t_w = (const float*)d_in[3];
  const float* t_b = (const float*)d_in[4];
  const float* p_w = (const float*)d_in[5];
  const float* p_b = (const float*)d_in[6];
  const float* w_w = (const float*)d_in[7];
  const float* w_b = (const float*)d_in[8];
  const float* gam = (const float*)d_in[9];
  const float* bet = (const float*)d_in[10];
  float* out = (float*)d_out;

  char* ws = (char*)d_ws;
  size_t off = 0;
  auto alloc = [&](size_t bytes) {
    char* p = ws + off; off += (bytes + 255) & ~(size_t)255; return p;
  };
  u16*  xT   = (u16*)alloc((size_t)Bn * Ln * Cn * 2);      // x^T bf16        8.4MB
  u16*  Wcat = (u16*)alloc((size_t)COn * Cn * 2);          // [theta;phi;g]   1.6MB
  u16*  Ww   = (u16*)alloc((size_t)Cn * CIn * 2);          // w_w bf16        0.5MB
  u16*  Qb   = (u16*)alloc((size_t)Bn * Hn * Ln * Dn * 2); // theta [B,H,L,D] 8.4MB
  u16*  Kb   = (u16*)alloc((size_t)Bn * Hn * Ln * Dn * 2); // phi   [B,H,L,D] 8.4MB
  u16*  Vt   = (u16*)alloc((size_t)Bn * Hn * Dn * Ln * 2); // g     [B,H,D,L] 8.4MB
  u16*  yT   = (u16*)alloc((size_t)Bn * Ln * CIn * 2);     // attn out        8.4MB
  u16*  wy   = (u16*)alloc((size_t)Bn * Cn * Ln * 2);      // pre-BN bf16     8.4MB
  float* st  = (float*)alloc(2 * Cn * 4);                  // BN sum/sumsq
  if (ws_size < off) return;  // ~53 MB required

  k_misc<<<dim3(64, 16, 5), 256, 0, stream>>>(x, g_w, t_w, p_w, w_w, xT, Wcat, Ww, st);
  k_proj<<<dim3(16, 12, 4), 256, 0, stream>>>(Wcat, xT, t_b, p_b, g_b, Qb, Kb, Vt);
  k_attn<<<dim3(16, 8, 4), 256, 0, stream>>>(Qb, Kb, Vt, yT);
  k_wgemm<<<dim3(16, 8, 4), 256, 0, stream>>>(Ww, yT, w_b, wy, st);
  k_bn<<<dim3(2048), 256, 0, stream>>>(wy, st, gam, bet, out);
}